// Round 3
// baseline (1031.953 us; speedup 1.0000x reference)
//
#include <hip/hip_runtime.h>
#include <math.h>

#define EPS 1e-6f

__device__ __forceinline__ float bcast(float x, int srcLane) {
    return __int_as_float(__builtin_amdgcn_readlane(__float_as_int(x), srcLane));
}

// One wave per batch pair; lane i = row i, all data in registers.
// Round-3 structure: phase-split to keep peak register pressure under the
// 256-reg budget of __launch_bounds__(256,2) so the allocator stays in arch
// VGPRs (round 2: arrays landed in AGPRs -> accvgpr shuffles -> 2x VALU
// inflation; rocprof showed VGPR=80 but occupancy implied ~200+ unified regs).
__global__ __launch_bounds__(256, 2) void vae_rec_kernel(const float* __restrict__ recon,
                                                         const float* __restrict__ orig,
                                                         float* __restrict__ out,
                                                         int npairs) {
    const int lane = threadIdx.x & 63;
    const int waveInBlock = threadIdx.x >> 6;
    const int pair = blockIdx.x * 4 + waveInBlock;

    float kl = 0.0f;
    if (pair < npairs) {
        const float* Bm = recon + (size_t)pair * 4096;
        const float* Am = orig + (size_t)pair * 4096;

        // ---- Phase 1: load B, Cholesky(B). ~80 live regs. ----
        float rB[64];
        {
            const float4* pb = (const float4*)(Bm + lane * 64);
#pragma unroll
            for (int i = 0; i < 16; ++i) {
                float4 v = pb[i];
                rB[4 * i + 0] = v.x; rB[4 * i + 1] = v.y;
                rB[4 * i + 2] = v.z; rB[4 * i + 3] = v.w;
            }
        }
        float detB = 1.0f;
#pragma unroll
        for (int k = 0; k < 64; ++k) {
            float bkk = bcast(rB[k], k);
            detB *= bkk;
            float ib = __builtin_amdgcn_rsqf(bkk);
            rB[k] *= ib;  // L_B[lane][k] for lane >= k
#pragma unroll
            for (int j = k + 1; j < 64; ++j) {
                float c = bcast(rB[k], j);
                rB[j] = __builtin_fmaf(-rB[k], c, rB[j]);
            }
        }

        // Pin the phase boundary: don't let the scheduler hoist A's loads
        // (64 regs of pressure) into phase 1.
        __builtin_amdgcn_sched_barrier(0);

        // ---- Phase 2: load A; fused Cholesky(A) + forward substitution. ----
        // Valid interleave: subst step k reads/writes rA[c<=k] only after
        // A-step k finalized column k; A-steps >k touch only rA[j>k].
        // rB[k] dies at step k -> pressure decreases monotonically.
        float rA[64];
        {
            const float4* pa = (const float4*)(Am + lane * 64);
#pragma unroll
            for (int i = 0; i < 16; ++i) {
                float4 v = pa[i];
                rA[4 * i + 0] = v.x; rA[4 * i + 1] = v.y;
                rA[4 * i + 2] = v.z; rA[4 * i + 3] = v.w;
            }
        }
        float detA = 1.0f, fro = 0.0f;
#pragma unroll
        for (int k = 0; k < 64; ++k) {
            // Cholesky(A) step k
            float akk = bcast(rA[k], k);
            detA *= akk;
            float ia = __builtin_amdgcn_rsqf(akk);
            rA[k] *= ia;
#pragma unroll
            for (int j = k + 1; j < 64; ++j) {
                float c = bcast(rA[k], j);
                rA[j] = __builtin_fmaf(-rA[k], c, rA[j]);
            }
            // Forward-substitution step k: row k of W = L_B^{-1} L_A.
            float bii = bcast(rB[k], k);
            float inv = __builtin_amdgcn_rcpf(bii);
            float t = rB[k] * inv;  // per-lane m: L_B[m][k]/L_B[k][k]
            float acc = 0.0f;
#pragma unroll
            for (int c2 = 0; c2 <= k; ++c2) {
                float u = bcast(rA[c2], k);           // W[k][c2]*bii (uniform)
                acc = __builtin_fmaf(u, u, acc);      // uniform sum of u^2
                rA[c2] = __builtin_fmaf(-t, u, rA[c2]); // residual update m>k
            }
            fro = __builtin_fmaf(acc, inv * inv, fro);
        }

        float sdetB = __builtin_sqrtf(detB);
        float sdetA = __builtin_sqrtf(detA);
        float logdet = __builtin_logf((sdetA + EPS) / (sdetB + EPS));
        kl = 0.5f * (fro - 64.0f + logdet);
    }

    __shared__ float sred[4];
    if (lane == 0) sred[waveInBlock] = kl;
    __syncthreads();
    if (threadIdx.x == 0) {
        float s = sred[0] + sred[1] + sred[2] + sred[3];
        atomicAdd(out + 1, -s);
    }
}

// Encoded: 32x32 Cholesky (sqrt-det) + trace. Two matrices per wave (lanes
// 0-31 / 32-63); broadcasts via two static readlanes + select on the half.
__global__ __launch_bounds__(256, 1) void vae_enc_kernel(const float* __restrict__ enc,
                                                         float* __restrict__ out,
                                                         int nmats) {
    const int lane = threadIdx.x & 63;
    const int r = lane & 31;
    const bool hi = lane >= 32;
    const int wv = (int)(blockIdx.x * 4 + (threadIdx.x >> 6));
    const int mat = wv * 2 + (hi ? 1 : 0);

    float kl = 0.0f;
    if (mat < nmats) {
        const float* M = enc + (size_t)mat * 1024;
        float rm[32];
        {
            const float4* pm = (const float4*)(M + r * 32);
#pragma unroll
            for (int i = 0; i < 8; ++i) {
                float4 v = pm[i];
                rm[4 * i + 0] = v.x; rm[4 * i + 1] = v.y;
                rm[4 * i + 2] = v.z; rm[4 * i + 3] = v.w;
            }
        }

        // trace: own diagonal element, butterfly-reduce within the half
        float tr = 0.0f;
#pragma unroll
        for (int i = 0; i < 32; ++i)
            if (i == r) tr = rm[i];
#pragma unroll
        for (int m = 1; m < 32; m <<= 1)
            tr += __shfl_xor(tr, m, 64);

        float det = 1.0f;
#pragma unroll
        for (int k = 0; k < 32; ++k) {
            float a0 = bcast(rm[k], k);
            float a1 = bcast(rm[k], k + 32);
            float akk = hi ? a1 : a0;
            det *= akk;
            float inv = __builtin_amdgcn_rsqf(akk);
            rm[k] *= inv;
#pragma unroll
            for (int j = k + 1; j < 32; ++j) {
                float l0 = bcast(rm[k], j);
                float l1 = bcast(rm[k], j + 32);
                float ljk = hi ? l1 : l0;
                rm[j] = __builtin_fmaf(-rm[k], ljk, rm[j]);
            }
        }

        float sdet = __builtin_sqrtf(det);
        float logdet = __builtin_logf((sdet + EPS) / (1.0f + EPS));
        kl = 0.5f * (tr - 32.0f + logdet);
    }

    __shared__ float sred[8];
    if (r == 0) sred[threadIdx.x >> 5] = kl;
    __syncthreads();
    if (threadIdx.x == 0) {
        float s = 0.0f;
#pragma unroll
        for (int i = 0; i < 8; ++i) s += sred[i];
        atomicAdd(out + 2, -s);
    }
}

__global__ void vae_init_kernel(float* __restrict__ out) {
    if (threadIdx.x < 3) out[threadIdx.x] = 0.0f;
}

__global__ void vae_final_kernel(float* __restrict__ out) {
    if (threadIdx.x == 0) out[0] = out[1] + out[2];
}

extern "C" void kernel_launch(void* const* d_in, const int* in_sizes, int n_in,
                              void* d_out, int out_size, void* d_ws, size_t ws_size,
                              hipStream_t stream) {
    const float* recon = (const float*)d_in[0];
    const float* orig = (const float*)d_in[1];
    const float* enc = (const float*)d_in[2];
    float* out = (float*)d_out;

    const int npairs = in_sizes[0] / 4096;   // 8192
    const int nmats = in_sizes[2] / 1024;    // 8192

    vae_init_kernel<<<1, 64, 0, stream>>>(out);

    const int rec_blocks = (npairs + 3) / 4;          // 4 waves/block, 1 pair/wave
    vae_rec_kernel<<<rec_blocks, 256, 0, stream>>>(recon, orig, out, npairs);

    const int enc_blocks = (nmats + 7) / 8;           // 8 matrices/block (2 per wave)
    vae_enc_kernel<<<enc_blocks, 256, 0, stream>>>(enc, out, nmats);

    vae_final_kernel<<<1, 64, 0, stream>>>(out);
}

// Round 4
// 468.633 us; speedup vs baseline: 2.2021x; 2.2021x over previous
//
#include <hip/hip_runtime.h>
#include <math.h>

#define EPS 1e-6f

__device__ __forceinline__ float bcast(float x, int srcLane) {
    return __int_as_float(__builtin_amdgcn_readlane(__float_as_int(x), srcLane));
}

// Packed lower-triangular storage for L_B in LDS: column k (rows k..63) at
// offset off(k) = sum_{j<k}(64-j); 2080 floats + 64 dump slots for lanes<k.
constexpr int TRI = 2080;
constexpr int WSLOT = TRI + 64;  // 8576 B per wave

// One wave per batch pair; lane i = row i. Phase-split: Cholesky(B) with B in
// registers, staging L_B columns into packed LDS; then Cholesky(A) fused with
// forward substitution, streaming L_B columns back from LDS. Keeps peak live
// registers ~100 so the allocator stays in arch VGPRs (round 2: ~200 live ->
// AGPR traffic, 2x VALU; round 3: 256-reg cap -> scratch spills, 3x time).
__global__ __launch_bounds__(256, 1) void vae_rec_kernel(const float* __restrict__ recon,
                                                         const float* __restrict__ orig,
                                                         float* __restrict__ out,
                                                         int npairs) {
    const int lane = threadIdx.x & 63;
    const int waveInBlock = threadIdx.x >> 6;
    const int pair = blockIdx.x * 4 + waveInBlock;

    __shared__ float lds[4 * WSLOT];
    float* wl = lds + waveInBlock * WSLOT;

    float kl = 0.0f;
    if (pair < npairs) {
        const float* Bm = recon + (size_t)pair * 4096;
        const float* Am = orig + (size_t)pair * 4096;

        // ---- Phase 1: load B, Cholesky(B), stage columns to LDS ----
        float detB;
        {
            float rB[64];
            const float4* pb = (const float4*)(Bm + lane * 64);
#pragma unroll
            for (int i = 0; i < 16; ++i) {
                float4 v = pb[i];
                rB[4 * i + 0] = v.x; rB[4 * i + 1] = v.y;
                rB[4 * i + 2] = v.z; rB[4 * i + 3] = v.w;
            }
            detB = 1.0f;
            int off = 0;  // constant-folded by full unroll
#pragma unroll
            for (int k = 0; k < 64; ++k) {
                float bkk = bcast(rB[k], k);
                detB *= bkk;
                float ib = __builtin_amdgcn_rsqf(bkk);
                float lk = rB[k] * ib;  // L_B[lane][k], valid for lane >= k
                // packed column write; lanes < k go to the dump region
                int idx = (lane >= k) ? (off + lane - k) : (TRI + lane);
                wl[idx] = lk;
                off += 64 - k;
#pragma unroll
                for (int j = k + 1; j < 64; ++j) {
                    float c = bcast(lk, j);  // L_B[j][k]
                    rB[j] = __builtin_fmaf(-lk, c, rB[j]);
                }
            }
        }  // rB dead here

        // ---- Phase 2: load A; fused Cholesky(A) + forward substitution ----
        float rA[64];
        {
            const float4* pa = (const float4*)(Am + lane * 64);
#pragma unroll
            for (int i = 0; i < 16; ++i) {
                float4 v = pa[i];
                rA[4 * i + 0] = v.x; rA[4 * i + 1] = v.y;
                rA[4 * i + 2] = v.z; rA[4 * i + 3] = v.w;
            }
        }
        float detA = 1.0f, fro = 0.0f;
        int off = 0;
#pragma unroll
        for (int k = 0; k < 64; ++k) {
            // Cholesky(A) step k
            float akk = bcast(rA[k], k);
            detA *= akk;
            float ia = __builtin_amdgcn_rsqf(akk);
            rA[k] *= ia;  // finalize column k of L_A (lanes >= k)
#pragma unroll
            for (int j = k + 1; j < 64; ++j) {
                float c = bcast(rA[k], j);
                rA[j] = __builtin_fmaf(-rA[k], c, rA[j]);
            }
            // Substitution step k: row k of W = L_B^{-1} L_A.
            int idx = off + ((lane >= k) ? (lane - k) : 0);  // sub-k lanes: broadcast read
            float cB = wl[idx];                               // L_B[lane][k]
            off += 64 - k;
            float bii = bcast(cB, k);
            float inv = __builtin_amdgcn_rcpf(bii);
            float t = cB * inv;  // L_B[lane][k]/L_B[k][k]
            float acc = 0.0f;
#pragma unroll
            for (int c2 = 0; c2 <= k; ++c2) {
                float u = bcast(rA[c2], k);             // residual row k (uniform)
                acc = __builtin_fmaf(u, u, acc);        // uniform sum of u^2
                rA[c2] = __builtin_fmaf(-t, u, rA[c2]); // residual update (m > k)
            }
            fro = __builtin_fmaf(acc, inv * inv, fro);
        }

        float sdetB = __builtin_sqrtf(detB);
        float sdetA = __builtin_sqrtf(detA);
        float logdet = __builtin_logf((sdetA + EPS) / (sdetB + EPS));
        kl = 0.5f * (fro - 64.0f + logdet);
    }

    __shared__ float sred[4];
    if (lane == 0) sred[waveInBlock] = kl;
    __syncthreads();
    if (threadIdx.x == 0) {
        float s = sred[0] + sred[1] + sred[2] + sred[3];
        atomicAdd(out + 1, -s);
    }
}

// Encoded: 32x32 Cholesky (sqrt-det) + trace. Two matrices per wave (lanes
// 0-31 / 32-63); broadcasts via two static readlanes + select on the half.
__global__ __launch_bounds__(256, 1) void vae_enc_kernel(const float* __restrict__ enc,
                                                         float* __restrict__ out,
                                                         int nmats) {
    const int lane = threadIdx.x & 63;
    const int r = lane & 31;
    const bool hi = lane >= 32;
    const int wv = (int)(blockIdx.x * 4 + (threadIdx.x >> 6));
    const int mat = wv * 2 + (hi ? 1 : 0);

    float kl = 0.0f;
    if (mat < nmats) {
        const float* M = enc + (size_t)mat * 1024;
        float rm[32];
        {
            const float4* pm = (const float4*)(M + r * 32);
#pragma unroll
            for (int i = 0; i < 8; ++i) {
                float4 v = pm[i];
                rm[4 * i + 0] = v.x; rm[4 * i + 1] = v.y;
                rm[4 * i + 2] = v.z; rm[4 * i + 3] = v.w;
            }
        }

        float tr = 0.0f;
#pragma unroll
        for (int i = 0; i < 32; ++i)
            if (i == r) tr = rm[i];
#pragma unroll
        for (int m = 1; m < 32; m <<= 1)
            tr += __shfl_xor(tr, m, 64);

        float det = 1.0f;
#pragma unroll
        for (int k = 0; k < 32; ++k) {
            float a0 = bcast(rm[k], k);
            float a1 = bcast(rm[k], k + 32);
            float akk = hi ? a1 : a0;
            det *= akk;
            float inv = __builtin_amdgcn_rsqf(akk);
            rm[k] *= inv;
#pragma unroll
            for (int j = k + 1; j < 32; ++j) {
                float l0 = bcast(rm[k], j);
                float l1 = bcast(rm[k], j + 32);
                float ljk = hi ? l1 : l0;
                rm[j] = __builtin_fmaf(-rm[k], ljk, rm[j]);
            }
        }

        float sdet = __builtin_sqrtf(det);
        float logdet = __builtin_logf((sdet + EPS) / (1.0f + EPS));
        kl = 0.5f * (tr - 32.0f + logdet);
    }

    __shared__ float sred[8];
    if (r == 0) sred[threadIdx.x >> 5] = kl;
    __syncthreads();
    if (threadIdx.x == 0) {
        float s = 0.0f;
#pragma unroll
        for (int i = 0; i < 8; ++i) s += sred[i];
        atomicAdd(out + 2, -s);
    }
}

__global__ void vae_init_kernel(float* __restrict__ out) {
    if (threadIdx.x < 3) out[threadIdx.x] = 0.0f;
}

__global__ void vae_final_kernel(float* __restrict__ out) {
    if (threadIdx.x == 0) out[0] = out[1] + out[2];
}

extern "C" void kernel_launch(void* const* d_in, const int* in_sizes, int n_in,
                              void* d_out, int out_size, void* d_ws, size_t ws_size,
                              hipStream_t stream) {
    const float* recon = (const float*)d_in[0];
    const float* orig = (const float*)d_in[1];
    const float* enc = (const float*)d_in[2];
    float* out = (float*)d_out;

    const int npairs = in_sizes[0] / 4096;   // 8192
    const int nmats = in_sizes[2] / 1024;    // 8192

    vae_init_kernel<<<1, 64, 0, stream>>>(out);

    const int rec_blocks = (npairs + 3) / 4;          // 4 waves/block, 1 pair/wave
    vae_rec_kernel<<<rec_blocks, 256, 0, stream>>>(recon, orig, out, npairs);

    const int enc_blocks = (nmats + 7) / 8;           // 8 matrices/block (2 per wave)
    vae_enc_kernel<<<enc_blocks, 256, 0, stream>>>(enc, out, nmats);

    vae_final_kernel<<<1, 64, 0, stream>>>(out);
}